// Round 8
// baseline (108.974 us; speedup 1.0000x reference)
//
#include <hip/hip_runtime.h>
#include <hip/hip_bf16.h>

#define TT 256   // sequence length
#define CE 384   // embed
#define HD 64    // head size

typedef __attribute__((ext_vector_type(8))) short short8v;
typedef __attribute__((ext_vector_type(4))) float float4v;
typedef __attribute__((ext_vector_type(4))) unsigned int uint4v;
typedef __attribute__((ext_vector_type(4))) unsigned short ushort4v;

#define SCALE 0.05103103630798287f  // 384^-0.5 (reference scales by C, not H)

__device__ __forceinline__ unsigned short f2bf(float f) {
    union { __hip_bfloat16 b; unsigned short u; } cv;
    cv.b = __float2bfloat16(f);   // RNE; pairs fuse to v_cvt_pk_bf16_f32
    return cv.u;
}
__device__ __forceinline__ unsigned int pk2(float a, float b) {
    return (unsigned int)f2bf(a) | ((unsigned int)f2bf(b) << 16);
}

// Swizzled LDS addressing: rows of 64 bf16 (128 B), 16B-chunk XOR swizzle
__device__ __forceinline__ int adr8(int row, int col) {
    return row * 128 + ((((col >> 3) ^ (row & 7)) & 7) << 4) + ((col & 7) << 1);
}

// raw barrier: drain LDS ops only -- global loads stay in flight
#define BAR() do {                                            \
    asm volatile("s_waitcnt lgkmcnt(0)" ::: "memory");        \
    __builtin_amdgcn_s_barrier();                             \
    __builtin_amdgcn_sched_barrier(0);                        \
} while (0)

// ---------------- kernel 0: weight transpose + bf16 convert -----------------
__global__ void wprep(const float* __restrict__ Wk, const float* __restrict__ Wq,
                      const float* __restrict__ Wv, unsigned short* __restrict__ Wt) {
    int idx = blockIdx.x * 256 + threadIdx.x;
    if (idx >= 3 * HD * CE) return;
    int w = idx / (HD * CE);
    int rem = idx - w * (HD * CE);
    int h = rem / CE;
    int c = rem - h * CE;
    const float* W = (w == 0) ? Wk : (w == 1) ? Wq : Wv;
    Wt[idx] = f2bf(W[c * HD + h]);
}

// ---------------- kernel 1: QKV projection GEMM (double-buffered) -----------
// 512 threads (8 waves), tile = 128 t-rows x 192 n-cols, grid = 512 batches x 2.
// LDS 80 KiB (2 x [Xs 16K | Ws 24K]) -> 2 blocks/CU; 1 barrier per K-chunk.
// X prefetch 2-deep (A/B reg sets); W 1-deep (L2-hot). acc = 12 f32x4 = 48.
__global__ __launch_bounds__(512, 4)
void qkv(const float* __restrict__ X, const unsigned short* __restrict__ Wt,
         unsigned short* __restrict__ Kb, unsigned short* __restrict__ Qb,
         unsigned short* __restrict__ Vt) {
    extern __shared__ char lds[];   // 81920 B: buf0 @0, buf1 @40960

    const int bid = blockIdx.x;
    const int b = bid >> 1, rh = bid & 1;       // batch, row-half
    const int tid = threadIdx.x;
    const int w = tid >> 6, l = tid & 63;
    const int l15 = l & 15, lq = l >> 4;

    const float* Xb = X + ((long)b * TT + rh * 128) * CE;

    // staging slots: X 1024 chunks/512thr = 2; W 1536/512 = 3
    const int xt0 = tid >> 3,        xk0 = tid & 7;
    const int xt1 = 64 + (tid >> 3), xk1 = tid & 7;
    const int wn0 = tid >> 3;
    const int wn1 = 64 + (tid >> 3);
    const int wn2 = 128 + (tid >> 3);
    const int wk = tid & 7;

    float4 xa0, xa1, xa2, xa3;   // X set A (chunk slots 0,1)
    float4 xb0, xb1, xb2, xb3;   // X set B
    uint4v wr0, wr1, wr2;        // W set (single)

    auto issueXA = [&](int kk) {
        const float* s0 = Xb + xt0 * CE + kk + xk0 * 8;
        xa0 = *(const float4*)s0;  xa1 = *(const float4*)(s0 + 4);
        const float* s1 = Xb + xt1 * CE + kk + xk1 * 8;
        xa2 = *(const float4*)s1;  xa3 = *(const float4*)(s1 + 4);
    };
    auto issueXB = [&](int kk) {
        const float* s0 = Xb + xt0 * CE + kk + xk0 * 8;
        xb0 = *(const float4*)s0;  xb1 = *(const float4*)(s0 + 4);
        const float* s1 = Xb + xt1 * CE + kk + xk1 * 8;
        xb2 = *(const float4*)s1;  xb3 = *(const float4*)(s1 + 4);
    };
    auto issueW = [&](int kk) {
        wr0 = *(const uint4v*)(Wt + wn0 * CE + kk + wk * 8);
        wr1 = *(const uint4v*)(Wt + wn1 * CE + kk + wk * 8);
        wr2 = *(const uint4v*)(Wt + wn2 * CE + kk + wk * 8);
    };
    auto storeXA = [&](char* Xs) {
        uint4v p0 = {pk2(xa0.x, xa0.y), pk2(xa0.z, xa0.w), pk2(xa1.x, xa1.y), pk2(xa1.z, xa1.w)};
        *(uint4v*)(Xs + xt0 * 128 + (((xk0 ^ (xt0 & 7)) & 7) << 4)) = p0;
        uint4v p1 = {pk2(xa2.x, xa2.y), pk2(xa2.z, xa2.w), pk2(xa3.x, xa3.y), pk2(xa3.z, xa3.w)};
        *(uint4v*)(Xs + xt1 * 128 + (((xk1 ^ (xt1 & 7)) & 7) << 4)) = p1;
    };
    auto storeXB = [&](char* Xs) {
        uint4v p0 = {pk2(xb0.x, xb0.y), pk2(xb0.z, xb0.w), pk2(xb1.x, xb1.y), pk2(xb1.z, xb1.w)};
        *(uint4v*)(Xs + xt0 * 128 + (((xk0 ^ (xt0 & 7)) & 7) << 4)) = p0;
        uint4v p1 = {pk2(xb2.x, xb2.y), pk2(xb2.z, xb2.w), pk2(xb3.x, xb3.y), pk2(xb3.z, xb3.w)};
        *(uint4v*)(Xs + xt1 * 128 + (((xk1 ^ (xt1 & 7)) & 7) << 4)) = p1;
    };
    auto storeW = [&](char* Ws) {
        *(uint4v*)(Ws + wn0 * 128 + (((wk ^ (wn0 & 7)) & 7) << 4)) = wr0;
        *(uint4v*)(Ws + wn1 * 128 + (((wk ^ (wn1 & 7)) & 7) << 4)) = wr1;
        *(uint4v*)(Ws + wn2 * 128 + (((wk ^ (wn2 & 7)) & 7) << 4)) = wr2;
    };

    const float4v fzero = {0.f, 0.f, 0.f, 0.f};
    float4v acc[12];
    #pragma unroll
    for (int j = 0; j < 12; ++j) acc[j] = fzero;

    auto mfma_phase = [&](const char* Xs, const char* Ws) {
        __builtin_amdgcn_s_setprio(1);
        #pragma unroll
        for (int ks = 0; ks < 2; ++ks) {
            short8v a = *(const short8v*)(Xs + adr8(w * 16 + l15, ks * 32 + lq * 8));
            #pragma unroll
            for (int nt = 0; nt < 12; ++nt) {
                short8v bb = *(const short8v*)(Ws + adr8(nt * 16 + l15, ks * 32 + lq * 8));
                acc[nt] = __builtin_amdgcn_mfma_f32_16x16x32_bf16(a, bb, acc[nt], 0, 0, 0);
            }
        }
        __builtin_amdgcn_s_setprio(0);
    };

    issueXA(0);
    issueXB(64);
    issueW(0);

    #pragma unroll
    for (int kp = 0; kp < 3; ++kp) {
        {   // even chunk 2kp -> buf0
            char* Xs = lds;  char* Ws = lds + 16384;
            storeXA(Xs);                 // waits A-regs' vmcnt; B + next stay in flight
            storeW(Ws);
            if (kp < 2) issueXA((2 * kp + 2) * 64);
            issueW((2 * kp + 1) * 64);   // FIX r8: was issueW(2*kp+1) -- chunk idx, not offset
            BAR();                       // buf0 visible; globals in flight
            mfma_phase(Xs, Ws);
        }
        {   // odd chunk 2kp+1 -> buf1
            char* Xs = lds + 40960;  char* Ws = lds + 57344;
            storeXB(Xs);
            storeW(Ws);
            if (kp < 2) { issueXB((2 * kp + 3) * 64); issueW((2 * kp + 2) * 64); }  // FIX r8
            BAR();
            mfma_phase(Xs, Ws);
        }
    }

    // epilogue: t = rh*128 + w*16 + lq*4 + r ; n = nt*16 + l15
    const int t0 = rh * 128 + w * 16 + lq * 4;
    #pragma unroll
    for (int nt = 0; nt < 12; ++nt) {
        const int n = nt * 16 + l15;
        if (n < 64) {              // K row-major [b][t][h]
            #pragma unroll
            for (int r = 0; r < 4; ++r)
                Kb[((long)b * TT + t0 + r) * HD + n] = f2bf(acc[nt][r]);
        } else if (n < 128) {      // Q row-major
            const int h = n - 64;
            #pragma unroll
            for (int r = 0; r < 4; ++r)
                Qb[((long)b * TT + t0 + r) * HD + h] = f2bf(acc[nt][r]);
        } else {                   // V transposed [b][h][t]
            const int h = n - 128;
            ushort4v pv;
            pv[0] = f2bf(acc[nt][0]);
            pv[1] = f2bf(acc[nt][1]);
            pv[2] = f2bf(acc[nt][2]);
            pv[3] = f2bf(acc[nt][3]);
            *(ushort4v*)(Vt + ((long)b * HD + h) * TT + t0) = pv;
        }
    }
}

// ---------------- kernel 2: attention (query-axis softmax) ------------------
// 512 threads (8 waves), one batch per block, 80 KiB LDS -> 2 blocks/CU.
// s in 4 slabs of 64, K/V prefetched 1 slab ahead (pk[2]/pv[2], unrolled).
// Raw BAR()s (lgkm-only) keep global loads in flight across phases.
__global__ __launch_bounds__(512, 4)
void attn(const unsigned short* __restrict__ Kb, const unsigned short* __restrict__ Qb,
          const unsigned short* __restrict__ Vt, float* __restrict__ out) {
    extern __shared__ char lds[];
    char* Qs  = lds;            // 32 KiB: 256 x 64 bf16 (adr8)
    char* Wts = lds + 32768;    // 32 KiB: 256 t-rows x 64 s-cols bf16 (adr8)
    char* Ks  = lds + 65536;    //  8 KiB: 64 x 64 bf16 (adr8); smx overlays
    char* Vts = lds + 73728;    //  8 KiB: 64 h-rows x 64 s-cols bf16 (adr8)
    float2* smx = (float2*)Ks;  // [2][64] (max,sum) -- valid only after QK^T

    const int b = blockIdx.x;
    const int tid = threadIdx.x;
    const int w = tid >> 6, l = tid & 63;
    const int l15 = l & 15, lq = l >> 4;
    const int sw = w & 3, th = w >> 2;
    const int vrow = tid >> 3, vc8 = tid & 7;

    // prologue: issue Q loads first, then slab-0 K/V (vmcnt order matters)
    uint4v qreg[4];
    #pragma unroll
    for (int j = 0; j < 4; ++j) {
        int ci = j * 512 + tid;
        qreg[j] = *(const uint4v*)(Qb + ((long)b * TT + (ci >> 3)) * HD + (ci & 7) * 8);
    }
    uint4v pk[2], pv[2];
    pk[0] = *(const uint4v*)(Kb + ((long)b * TT + vrow) * HD + vc8 * 8);
    pv[0] = *(const uint4v*)(Vt + ((long)b * HD + vrow) * TT + vc8 * 8);

    // write Q to LDS (waits only Q-regs' vmcnt; slab-0 loads stay in flight)
    #pragma unroll
    for (int j = 0; j < 4; ++j) {
        int ci = j * 512 + tid;
        int t = ci >> 3, k8 = ci & 7;
        *(uint4v*)(Qs + t * 128 + (((k8 ^ (t & 7)) & 7) << 4)) = qreg[j];
    }

    const float4v fzero = {0.f, 0.f, 0.f, 0.f};
    float4v o[2][4];
    #pragma unroll
    for (int i = 0; i < 2; ++i)
        #pragma unroll
        for (int j = 0; j < 4; ++j) o[i][j] = fzero;

    #pragma unroll
    for (int sb = 0; sb < 4; ++sb) {
        const int s0 = sb * 64;
        const int cur = sb & 1;
        BAR();   // prev PV/merge LDS reads drained -> Ks/Vts writable

        // stage current slab (waits pk/pv vmcnt), prefetch next slab
        *(uint4v*)(Ks + vrow * 128 + (((vc8 ^ (vrow & 7)) & 7) << 4)) = pk[cur];
        *(uint4v*)(Vts + vrow * 128 + (((vc8 ^ (vrow & 7)) & 7) << 4)) = pv[cur];
        if (sb < 3) {
            pk[cur ^ 1] = *(const uint4v*)(Kb + ((long)b * TT + s0 + 64 + vrow) * HD + vc8 * 8);
            pv[cur ^ 1] = *(const uint4v*)(Vt + ((long)b * HD + vrow) * TT + s0 + 64 + vc8 * 8);
        }
        BAR();   // Ks/Vts (and Qs at sb=0) visible; prefetch stays in flight

        // Z = K Q^T : z[tt], t = th*128 + tt*16 + l15, s-row = sw*16 + lq*4 + r
        float4v z[8];
        #pragma unroll
        for (int tt = 0; tt < 8; ++tt) z[tt] = fzero;
        __builtin_amdgcn_s_setprio(1);
        #pragma unroll
        for (int ks = 0; ks < 2; ++ks) {
            short8v ak = *(const short8v*)(Ks + adr8(sw * 16 + l15, ks * 32 + lq * 8));
            #pragma unroll
            for (int tt = 0; tt < 8; ++tt) {
                short8v bq = *(const short8v*)(Qs + adr8(th * 128 + tt * 16 + l15, ks * 32 + lq * 8));
                z[tt] = __builtin_amdgcn_mfma_f32_16x16x32_bf16(ak, bq, z[tt], 0, 0, 0);
            }
        }
        __builtin_amdgcn_s_setprio(0);
        BAR();   // QK^T LDS reads drained -> smx overlay safe

        // local softmax partials over this wave's t-half
        float pm[4], fac[4];
        #pragma unroll
        for (int r = 0; r < 4; ++r) {
            const int s = s0 + sw * 16 + lq * 4 + r;
            float mm = -1e30f;
            #pragma unroll
            for (int tt = 0; tt < 8; ++tt) {
                int t = th * 128 + tt * 16 + l15;
                float v = (t >= s) ? z[tt][r] * SCALE : -1e30f;  // causal: keep t >= s
                z[tt][r] = v;
                mm = fmaxf(mm, v);
            }
            mm = fmaxf(mm, __shfl_xor(mm, 1));
            mm = fmaxf(mm, __shfl_xor(mm, 2));
            mm = fmaxf(mm, __shfl_xor(mm, 4));
            mm = fmaxf(mm, __shfl_xor(mm, 8));
            float ps = 0.f;
            #pragma unroll
            for (int tt = 0; tt < 8; ++tt) {
                float p = (z[tt][r] > -1e29f) ? __expf(z[tt][r] - mm) : 0.f;
                z[tt][r] = p;
                ps += p;
            }
            ps += __shfl_xor(ps, 1);
            ps += __shfl_xor(ps, 2);
            ps += __shfl_xor(ps, 4);
            ps += __shfl_xor(ps, 8);
            pm[r] = mm;
            if (l15 == 0) smx[th * 64 + sw * 16 + lq * 4 + r] = make_float2(mm, ps);
        }
        BAR();   // partials visible

        // merge the two t-halves (online-softmax merge) -> normalize factor
        #pragma unroll
        for (int r = 0; r < 4; ++r) {
            const int row = sw * 16 + lq * 4 + r;
            float2 h0 = smx[row];
            float2 h1 = smx[64 + row];
            float m = fmaxf(h0.x, h1.x);
            float denom = h0.y * __expf(h0.x - m) + h1.y * __expf(h1.x - m);
            fac[r] = __expf(pm[r] - m) / denom;
        }

        // normalized weights -> Wts[t][s_local] (bf16, adr8)
        #pragma unroll
        for (int tt = 0; tt < 8; ++tt) {
            const int t = th * 128 + tt * 16 + l15;
            const int col = sw * 16 + lq * 4;
            ushort4v pw;
            pw[0] = f2bf(z[tt][0] * fac[0]);
            pw[1] = f2bf(z[tt][1] * fac[1]);
            pw[2] = f2bf(z[tt][2] * fac[2]);
            pw[3] = f2bf(z[tt][3] * fac[3]);
            *(ushort4v*)(Wts + t * 128 + ((((col >> 3) ^ (t & 7)) & 7) << 4) + ((col & 7) << 1)) = pw;
        }
        BAR();   // Wts visible

        // O += W V : wave owns t-rows w*32..+32, all 64 h; k = 64 slab cols
        __builtin_amdgcn_s_setprio(1);
        #pragma unroll
        for (int ks = 0; ks < 2; ++ks) {
            short8v aw0 = *(const short8v*)(Wts + adr8(w * 32 + l15,      ks * 32 + lq * 8));
            short8v aw1 = *(const short8v*)(Wts + adr8(w * 32 + 16 + l15, ks * 32 + lq * 8));
            #pragma unroll
            for (int ht = 0; ht < 4; ++ht) {
                short8v bv = *(const short8v*)(Vts + adr8(ht * 16 + l15, ks * 32 + lq * 8));
                o[0][ht] = __builtin_amdgcn_mfma_f32_16x16x32_bf16(aw0, bv, o[0][ht], 0, 0, 0);
                o[1][ht] = __builtin_amdgcn_mfma_f32_16x16x32_bf16(aw1, bv, o[1][ht], 0, 0, 0);
            }
        }
        __builtin_amdgcn_s_setprio(0);
    }

    // store O (f32, coalesced 64B per 16-lane group)
    #pragma unroll
    for (int rt = 0; rt < 2; ++rt)
        #pragma unroll
        for (int ht = 0; ht < 4; ++ht) {
            int t0 = w * 32 + rt * 16 + lq * 4;
            int h = ht * 16 + l15;
            #pragma unroll
            for (int r = 0; r < 4; ++r)
                out[((long)b * TT + t0 + r) * HD + h] = o[rt][ht][r];
        }
}

// ---------------------------------------------------------------------------
extern "C" void kernel_launch(void* const* d_in, const int* in_sizes, int n_in,
                              void* d_out, int out_size, void* d_ws, size_t ws_size,
                              hipStream_t stream) {
    const float* X  = (const float*)d_in[0];
    const float* Wk = (const float*)d_in[1];
    const float* Wq = (const float*)d_in[2];
    const float* Wv = (const float*)d_in[3];
    float* out = (float*)d_out;

    char* ws = (char*)d_ws;
    unsigned short* Wt = (unsigned short*)ws;                              // 147456 B
    unsigned short* Kb = (unsigned short*)(ws + 147456);                   // 16 MiB
    unsigned short* Qb = (unsigned short*)(ws + 147456 + 16777216L);       // 16 MiB
    unsigned short* Vt = (unsigned short*)(ws + 147456 + 2 * 16777216L);   // 16 MiB

    (void)hipFuncSetAttribute(reinterpret_cast<const void*>(qkv),
                              hipFuncAttributeMaxDynamicSharedMemorySize, 81920);
    (void)hipFuncSetAttribute(reinterpret_cast<const void*>(attn),
                              hipFuncAttributeMaxDynamicSharedMemorySize, 81920);

    wprep<<<288, 256, 0, stream>>>(Wk, Wq, Wv, Wt);
    qkv<<<1024, 512, 81920, stream>>>(X, Wt, Kb, Qb, Vt);
    attn<<<512, 512, 81920, stream>>>(Kb, Qb, Vt, out);
}

// Round 10
// 94.338 us; speedup vs baseline: 1.1551x; 1.1551x over previous
//
#include <hip/hip_runtime.h>
#include <hip/hip_bf16.h>

#define TT 256   // sequence length
#define CE 384   // embed
#define HD 64    // head size

typedef __attribute__((ext_vector_type(8))) short short8v;
typedef __attribute__((ext_vector_type(4))) float float4v;
typedef __attribute__((ext_vector_type(4))) unsigned int uint4v;
typedef __attribute__((ext_vector_type(4))) unsigned short ushort4v;

#define SCALE 0.05103103630798287f  // 384^-0.5 (reference scales by C, not H)

__device__ __forceinline__ unsigned short f2bf(float f) {
    union { __hip_bfloat16 b; unsigned short u; } cv;
    cv.b = __float2bfloat16(f);   // RNE; pairs fuse to v_cvt_pk_bf16_f32
    return cv.u;
}
__device__ __forceinline__ unsigned int pk2(float a, float b) {
    return (unsigned int)f2bf(a) | ((unsigned int)f2bf(b) << 16);
}
union u4s8 { uint4v u; short8v s; };

// Swizzled LDS addressing: rows of 64 bf16 (128 B), 16B-chunk XOR swizzle
__device__ __forceinline__ int adr8(int row, int col) {
    return row * 128 + ((((col >> 3) ^ (row & 7)) & 7) << 4) + ((col & 7) << 1);
}

// raw barrier: drain LDS ops, then barrier. NO sched_barrier pin (m141), and
// global loads in flight are NOT drained (no vmcnt).
#define BAR() do {                                            \
    asm volatile("s_waitcnt lgkmcnt(0)" ::: "memory");        \
    __builtin_amdgcn_s_barrier();                             \
} while (0)

// ---------------- kernel 0: weight transpose + bf16 convert -----------------
__global__ void wprep(const float* __restrict__ Wk, const float* __restrict__ Wq,
                      const float* __restrict__ Wv, unsigned short* __restrict__ Wt) {
    int idx = blockIdx.x * 256 + threadIdx.x;
    if (idx >= 3 * HD * CE) return;
    int w = idx / (HD * CE);
    int rem = idx - w * (HD * CE);
    int h = rem / CE;
    int c = rem - h * CE;
    const float* W = (w == 0) ? Wk : (w == 1) ? Wq : Wv;
    Wt[idx] = f2bf(W[c * HD + h]);
}

// ---------------- kernel 1: QKV projection GEMM (X direct-to-frag) ----------
// 512 threads (8 waves), tile = 128 t x 192 n, grid = 512 batches x 2 halves.
// X: NO LDS staging -- each wave loads its own A-fragments straight from HBM
// (16B contiguous per lane), 2 chunks deep. Only W staged (dbuf 2x24K LDS).
// One lgkm-barrier per chunk. acc = 48 VGPR; total ~117 -> 4 waves/SIMD.
__global__ __launch_bounds__(512, 4)
void qkv(const float* __restrict__ X, const unsigned short* __restrict__ Wt,
         unsigned short* __restrict__ Kb, unsigned short* __restrict__ Qb,
         unsigned short* __restrict__ Vt) {
    __shared__ char lds[49152];   // Ws dbuf: 24K @0, 24K @24576

    const int bid = blockIdx.x;
    const int b = bid >> 1, rh = bid & 1;
    const int tid = threadIdx.x;
    const int w = tid >> 6, l = tid & 63;
    const int l15 = l & 15, lq = l >> 4;

    const float* Xb = X + ((long)b * TT + rh * 128) * CE;
    const float* xrow = Xb + (w * 16 + l15) * CE + lq * 8;   // lane's A-frag row

    // W staging: 3 chunks/thread
    const int wn0 = tid >> 3, wn1 = 64 + (tid >> 3), wn2 = 128 + (tid >> 3);
    const int wk = tid & 7;

    uint4v wr0, wr1, wr2;
    auto issueW = [&](int kk) {
        wr0 = *(const uint4v*)(Wt + wn0 * CE + kk + wk * 8);
        wr1 = *(const uint4v*)(Wt + wn1 * CE + kk + wk * 8);
        wr2 = *(const uint4v*)(Wt + wn2 * CE + kk + wk * 8);
    };
    auto storeW = [&](char* Ws) {
        *(uint4v*)(Ws + wn0 * 128 + (((wk ^ (wn0 & 7)) & 7) << 4)) = wr0;
        *(uint4v*)(Ws + wn1 * 128 + (((wk ^ (wn1 & 7)) & 7) << 4)) = wr1;
        *(uint4v*)(Ws + wn2 * 128 + (((wk ^ (wn2 & 7)) & 7) << 4)) = wr2;
    };

    // X A-fragments, 2-deep: xf[set][ks][half]; literal indices (unrolled loop)
    float4 xf[2][2][2];
    auto issueX = [&](int set, int kk) {
        #pragma unroll
        for (int ks = 0; ks < 2; ++ks) {
            xf[set][ks][0] = *(const float4*)(xrow + kk + ks * 32);
            xf[set][ks][1] = *(const float4*)(xrow + kk + ks * 32 + 4);
        }
    };

    const float4v fzero = {0.f, 0.f, 0.f, 0.f};
    float4v acc[12];
    #pragma unroll
    for (int j = 0; j < 12; ++j) acc[j] = fzero;

    auto mfma_phase = [&](int set, const char* Ws) {
        #pragma unroll
        for (int ks = 0; ks < 2; ++ks) {
            u4s8 av;
            av.u[0] = pk2(xf[set][ks][0].x, xf[set][ks][0].y);
            av.u[1] = pk2(xf[set][ks][0].z, xf[set][ks][0].w);
            av.u[2] = pk2(xf[set][ks][1].x, xf[set][ks][1].y);
            av.u[3] = pk2(xf[set][ks][1].z, xf[set][ks][1].w);
            #pragma unroll
            for (int nt = 0; nt < 12; ++nt) {
                short8v bb = *(const short8v*)(Ws + adr8(nt * 16 + l15, ks * 32 + lq * 8));
                acc[nt] = __builtin_amdgcn_mfma_f32_16x16x32_bf16(av.s, bb, acc[nt], 0, 0, 0);
            }
        }
    };

    issueW(0);          // oldest -> storeW's wait drains only these
    issueX(0, 0);
    issueX(1, 64);

    #pragma unroll
    for (int kc = 0; kc < 6; ++kc) {
        char* Ws = lds + (kc & 1) * 24576;
        storeW(Ws);                       // waits wr vmcnt (counted, compiler)
        if (kc < 5) issueW((kc + 1) * 64);
        BAR();                            // Ws visible; X loads stay in flight
        mfma_phase(kc & 1, Ws);
        if (kc < 4) issueX(kc & 1, (kc + 2) * 64);   // refill used set, depth 2
    }

    // epilogue: t = rh*128 + w*16 + lq*4 + r ; n = nt*16 + l15
    const int t0 = rh * 128 + w * 16 + lq * 4;
    #pragma unroll
    for (int nt = 0; nt < 12; ++nt) {
        const int n = nt * 16 + l15;
        if (n < 64) {              // K row-major [b][t][h]
            #pragma unroll
            for (int r = 0; r < 4; ++r)
                Kb[((long)b * TT + t0 + r) * HD + n] = f2bf(acc[nt][r]);
        } else if (n < 128) {      // Q row-major
            const int h = n - 64;
            #pragma unroll
            for (int r = 0; r < 4; ++r)
                Qb[((long)b * TT + t0 + r) * HD + h] = f2bf(acc[nt][r]);
        } else {                   // V transposed [b][h][t]
            const int h = n - 128;
            ushort4v pv;
            pv[0] = f2bf(acc[nt][0]);
            pv[1] = f2bf(acc[nt][1]);
            pv[2] = f2bf(acc[nt][2]);
            pv[3] = f2bf(acc[nt][3]);
            *(ushort4v*)(Vt + ((long)b * HD + h) * TT + t0) = pv;
        }
    }
}

// ---------------- kernel 2: attention (query-axis softmax, K direct) --------
// 512 threads (8 waves), one batch per block, 73 KiB LDS -> 2 blocks/CU.
// K has zero cross-wave reuse -> A-frags load straight from global (L2-hot),
// prefetched 1 slab ahead. Q (4x reuse), V^T (8x), Wts stay in LDS.
// 3 lgkm-barriers per slab; no vmcnt drains anywhere in the loop.
__global__ __launch_bounds__(512, 4)
void attn(const unsigned short* __restrict__ Kb, const unsigned short* __restrict__ Qb,
          const unsigned short* __restrict__ Vt, float* __restrict__ out) {
    extern __shared__ char lds[];
    char* Qs  = lds;            // 32 KiB: 256 x 64 bf16 (adr8)
    char* Wts = lds + 32768;    // 32 KiB: 256 t-rows x 64 s-cols bf16 (adr8)
    char* Vts = lds + 65536;    //  8 KiB: 64 h-rows x 64 s-cols bf16 (adr8)
    float2* smx = (float2*)(lds + 73728);   // [2][64] float2 = 1024 B -> end 74752

    const int b = blockIdx.x;
    const int tid = threadIdx.x;
    const int w = tid >> 6, l = tid & 63;
    const int l15 = l & 15, lq = l >> 4;
    const int sw = w & 3, th = w >> 2;
    const int vrow = tid >> 3, vc8 = tid & 7;

    // lane's K-frag source: row = s0 + sw*16 + l15, k = ks*32 + lq*8
    const unsigned short* krow = Kb + ((long)b * TT + sw * 16 + l15) * HD + lq * 8;

    // prologue: Q loads first (oldest), then slab-0 V and K-frags
    uint4v qreg[4];
    #pragma unroll
    for (int j = 0; j < 4; ++j) {
        int ci = j * 512 + tid;
        qreg[j] = *(const uint4v*)(Qb + ((long)b * TT + (ci >> 3)) * HD + (ci & 7) * 8);
    }
    uint4v pv[2], kf[2][2];
    pv[0] = *(const uint4v*)(Vt + ((long)b * HD + vrow) * TT + vc8 * 8);
    kf[0][0] = *(const uint4v*)(krow);
    kf[0][1] = *(const uint4v*)(krow + 32);

    // write Q to LDS (counted vmcnt waits qreg only; V/K loads stay in flight)
    #pragma unroll
    for (int j = 0; j < 4; ++j) {
        int ci = j * 512 + tid;
        int t = ci >> 3, k8 = ci & 7;
        *(uint4v*)(Qs + t * 128 + (((k8 ^ (t & 7)) & 7) << 4)) = qreg[j];
    }

    const float4v fzero = {0.f, 0.f, 0.f, 0.f};
    float4v o[2][4];
    #pragma unroll
    for (int i = 0; i < 2; ++i)
        #pragma unroll
        for (int j = 0; j < 4; ++j) o[i][j] = fzero;

    #pragma unroll
    for (int sb = 0; sb < 4; ++sb) {
        const int s0 = sb * 64;
        const int cur = sb & 1, nxt = cur ^ 1;
        BAR();   // prev PV reads of Vts/Wts done; Qs visible at sb=0

        // stage current V slab; prefetch next slab's V + K-frags
        *(uint4v*)(Vts + vrow * 128 + (((vc8 ^ (vrow & 7)) & 7) << 4)) = pv[cur];
        if (sb < 3) {
            pv[nxt] = *(const uint4v*)(Vt + ((long)b * HD + vrow) * TT + s0 + 64 + vc8 * 8);
            kf[nxt][0] = *(const uint4v*)(krow + (long)(s0 + 64) * HD);
            kf[nxt][1] = *(const uint4v*)(krow + (long)(s0 + 64) * HD + 32);
        }

        // Z = K Q^T : A-frags direct from regs, B from Qs
        float4v z[8];
        #pragma unroll
        for (int tt = 0; tt < 8; ++tt) z[tt] = fzero;
        #pragma unroll
        for (int ks = 0; ks < 2; ++ks) {
            u4s8 ak; ak.u = kf[cur][ks];
            #pragma unroll
            for (int tt = 0; tt < 8; ++tt) {
                short8v bq = *(const short8v*)(Qs + adr8(th * 128 + tt * 16 + l15, ks * 32 + lq * 8));
                z[tt] = __builtin_amdgcn_mfma_f32_16x16x32_bf16(ak.s, bq, z[tt], 0, 0, 0);
            }
        }

        // local softmax partials over this wave's t-half
        float pm[4], fac[4];
        #pragma unroll
        for (int r = 0; r < 4; ++r) {
            const int s = s0 + sw * 16 + lq * 4 + r;
            float mm = -1e30f;
            #pragma unroll
            for (int tt = 0; tt < 8; ++tt) {
                int t = th * 128 + tt * 16 + l15;
                float v = (t >= s) ? z[tt][r] * SCALE : -1e30f;  // causal: keep t >= s
                z[tt][r] = v;
                mm = fmaxf(mm, v);
            }
            mm = fmaxf(mm, __shfl_xor(mm, 1));
            mm = fmaxf(mm, __shfl_xor(mm, 2));
            mm = fmaxf(mm, __shfl_xor(mm, 4));
            mm = fmaxf(mm, __shfl_xor(mm, 8));
            float ps = 0.f;
            #pragma unroll
            for (int tt = 0; tt < 8; ++tt) {
                float p = (z[tt][r] > -1e29f) ? __expf(z[tt][r] - mm) : 0.f;
                z[tt][r] = p;
                ps += p;
            }
            ps += __shfl_xor(ps, 1);
            ps += __shfl_xor(ps, 2);
            ps += __shfl_xor(ps, 4);
            ps += __shfl_xor(ps, 8);
            pm[r] = mm;
            if (l15 == 0) smx[th * 64 + sw * 16 + lq * 4 + r] = make_float2(mm, ps);
        }
        BAR();   // smx + Vts visible

        // merge the two t-halves (online-softmax merge) -> normalize factor
        #pragma unroll
        for (int r = 0; r < 4; ++r) {
            const int row = sw * 16 + lq * 4 + r;
            float2 h0 = smx[row];
            float2 h1 = smx[64 + row];
            float m = fmaxf(h0.x, h1.x);
            float denom = h0.y * __expf(h0.x - m) + h1.y * __expf(h1.x - m);
            fac[r] = __expf(pm[r] - m) / denom;
        }

        // normalized weights -> Wts[t][s_local] (bf16, adr8)
        #pragma unroll
        for (int tt = 0; tt < 8; ++tt) {
            const int t = th * 128 + tt * 16 + l15;
            const int col = sw * 16 + lq * 4;
            ushort4v pw;
            pw[0] = f2bf(z[tt][0] * fac[0]);
            pw[1] = f2bf(z[tt][1] * fac[1]);
            pw[2] = f2bf(z[tt][2] * fac[2]);
            pw[3] = f2bf(z[tt][3] * fac[3]);
            *(ushort4v*)(Wts + t * 128 + ((((col >> 3) ^ (t & 7)) & 7) << 4) + ((col & 7) << 1)) = pw;
        }
        BAR();   // Wts visible

        // O += W V : wave owns t-rows w*32..+32, all 64 h; k = 64 slab cols
        #pragma unroll
        for (int ks = 0; ks < 2; ++ks) {
            short8v aw0 = *(const short8v*)(Wts + adr8(w * 32 + l15,      ks * 32 + lq * 8));
            short8v aw1 = *(const short8v*)(Wts + adr8(w * 32 + 16 + l15, ks * 32 + lq * 8));
            #pragma unroll
            for (int ht = 0; ht < 4; ++ht) {
                short8v bv = *(const short8v*)(Vts + adr8(ht * 16 + l15, ks * 32 + lq * 8));
                o[0][ht] = __builtin_amdgcn_mfma_f32_16x16x32_bf16(aw0, bv, o[0][ht], 0, 0, 0);
                o[1][ht] = __builtin_amdgcn_mfma_f32_16x16x32_bf16(aw1, bv, o[1][ht], 0, 0, 0);
            }
        }
    }

    // store O (f32, coalesced 64B per 16-lane group)
    #pragma unroll
    for (int rt = 0; rt < 2; ++rt)
        #pragma unroll
        for (int ht = 0; ht < 4; ++ht) {
            int t0 = w * 32 + rt * 16 + lq * 4;
            int h = ht * 16 + l15;
            #pragma unroll
            for (int r = 0; r < 4; ++r)
                out[((long)b * TT + t0 + r) * HD + h] = o[rt][ht][r];
        }
}

// ---------------------------------------------------------------------------
extern "C" void kernel_launch(void* const* d_in, const int* in_sizes, int n_in,
                              void* d_out, int out_size, void* d_ws, size_t ws_size,
                              hipStream_t stream) {
    const float* X  = (const float*)d_in[0];
    const float* Wk = (const float*)d_in[1];
    const float* Wq = (const float*)d_in[2];
    const float* Wv = (const float*)d_in[3];
    float* out = (float*)d_out;

    char* ws = (char*)d_ws;
    unsigned short* Wt = (unsigned short*)ws;                              // 147456 B
    unsigned short* Kb = (unsigned short*)(ws + 147456);                   // 16 MiB
    unsigned short* Qb = (unsigned short*)(ws + 147456 + 16777216L);       // 16 MiB
    unsigned short* Vt = (unsigned short*)(ws + 147456 + 2 * 16777216L);   // 16 MiB

    // FIX r10: attn LDS = 74752 (Qs 32K + Wts 32K + Vts 8K + smx 1K); r9's
    // 74240 truncated smx -> OOB garbage partials -> NaN.
    (void)hipFuncSetAttribute(reinterpret_cast<const void*>(attn),
                              hipFuncAttributeMaxDynamicSharedMemorySize, 74752);

    wprep<<<288, 256, 0, stream>>>(Wk, Wq, Wv, Wt);
    qkv<<<1024, 512, 0, stream>>>(X, Wt, Kb, Qb, Vt);
    attn<<<512, 512, 74752, stream>>>(Kb, Qb, Vt, out);
}